// Round 4
// baseline (161.218 us; speedup 1.0000x reference)
//
#include <hip/hip_runtime.h>
#include <hip/hip_bf16.h>
#include <hip/hip_fp16.h>

#define IN_CH 128
#define OUT_CH 64
#define NB 256          // edge-chunk blocks for histo/scatter (chunk = 3125)
#define CHUNK_CAP 3200  // LDS staging capacity in scatter
#define SORT_CAP 6144   // LDS staging capacity in sort (mean bucket = 4096)

typedef _Float16 hh2 __attribute__((ext_vector_type(2)));   // native half2 for v_dot2

// ============================================================================
// K1 (fat): blocks [0,GB) do GEMM z0 = fp16(X @ W^T)  (NO dis scaling);
//           blocks [GB,GB+NB) do the per-chunk 256-bucket histogram.
// The two parts are data-independent; merging removes one launch and overlaps
// BW-heavy GEMM with atomic-heavy histogram.
// ============================================================================
__global__ void __launch_bounds__(256) fat1_kernel(const float* __restrict__ x,
                                                   const float* __restrict__ W,
                                                   __half* __restrict__ z0,
                                                   const int* __restrict__ col,
                                                   int* __restrict__ rawcnt,
                                                   int n, int E, int chunk, int GB) {
    __shared__ char smraw[64 * 66 * 2 * 2 * 2];   // 33792 B, aliased by both parts
    int t = threadIdx.x;

    if (blockIdx.x >= GB) {
        // ---- histogram part ----
        int* h = (int*)smraw;
        int blk = blockIdx.x - GB;
        h[t] = 0;
        __syncthreads();
        int s = blk * chunk, e = min(s + chunk, E);
        for (int i = s + t; i < e; i += 256)
            atomicAdd(&h[col[i] >> 8], 1);          // LDS atomic
        __syncthreads();
        rawcnt[blk * 256 + t] = h[t];               // coalesced
        return;
    }

    // ---- GEMM part (identical to verified r3 gemm, minus dis scaling) ----
    hh2* Xs = (hh2*)smraw;              // 64*66 half2
    hh2* Ws = Xs + 64 * 66;
    int m0 = blockIdx.x * 64;
#pragma unroll
    for (int r = 0; r < 8; ++r) {               // stage W: 64x128 fp32 -> half2
        int f = t + 256 * r;                    // float4 index; row=f>>5, kq=f&31
        int o = f >> 5, kq = f & 31;
        float4 w = ((const float4*)W)[f];
        Ws[o * 66 + kq * 2]     = hh2{(_Float16)w.x, (_Float16)w.y};
        Ws[o * 66 + kq * 2 + 1] = hh2{(_Float16)w.z, (_Float16)w.w};
    }
#pragma unroll
    for (int r = 0; r < 8; ++r) {               // stage X tile (clamped tail)
        int f = t + 256 * r;
        int node = f >> 5, kq = f & 31;
        int gv = min(m0 + node, n - 1);
        float4 xv = ((const float4*)(x + (size_t)gv * IN_CH))[kq];
        Xs[node * 66 + kq * 2]     = hh2{(_Float16)xv.x, (_Float16)xv.y};
        Xs[node * 66 + kq * 2 + 1] = hh2{(_Float16)xv.z, (_Float16)xv.w};
    }
    __syncthreads();
    int tx = t & 15, ty = t >> 4;
    float acc[4][4];
#pragma unroll
    for (int i = 0; i < 4; ++i)
#pragma unroll
        for (int j = 0; j < 4; ++j) acc[i][j] = 0.f;
#pragma unroll 4
    for (int kq = 0; kq < 32; ++kq) {           // 4 k-values per step
        hh2 xa0[4], xa1[4], wb0[4], wb1[4];
#pragma unroll
        for (int i = 0; i < 4; ++i) {
            int base = (tx + 16 * i) * 66 + kq * 2;
            xa0[i] = Xs[base]; xa1[i] = Xs[base + 1];
        }
#pragma unroll
        for (int j = 0; j < 4; ++j) {
            int base = (ty * 4 + j) * 66 + kq * 2;
            wb0[j] = Ws[base]; wb1[j] = Ws[base + 1];
        }
#pragma unroll
        for (int i = 0; i < 4; ++i)
#pragma unroll
            for (int j = 0; j < 4; ++j) {
                float s = acc[i][j];
                s = __builtin_amdgcn_fdot2(xa0[i], wb0[j], s, false);
                s = __builtin_amdgcn_fdot2(xa1[i], wb1[j], s, false);
                acc[i][j] = s;
            }
    }
#pragma unroll
    for (int i = 0; i < 4; ++i) {
        int v = m0 + tx + 16 * i;
        if (v < n) {
            union { __half2 h[2]; float2 f; } u;
            u.h[0] = __floats2half2_rn(acc[i][0], acc[i][1]);
            u.h[1] = __floats2half2_rn(acc[i][2], acc[i][3]);
            *(float2*)&z0[(size_t)v * OUT_CH + ty * 4] = u.f;   // 8B aligned
        }
    }
}

// ============================================================================
// K2: scatter edges into bucket-contiguous tmp. The per-bucket bases and this
// block's prefix are re-derived in-block from rawcnt (replaces scanblk kernel):
//   T[k]   = sum_b rawcnt[b][k]        (bucket totals)
//   P[k]   = sum_{b<blk} rawcnt[b][k]  (this block's offset within bucket)
//   B[k]   = exclusive scan_k of T     (bucket bases)
//   loff[k]= exclusive scan_k of own counts (local staging offsets)
// ============================================================================
__global__ void __launch_bounds__(512) scatter_kernel(const int* __restrict__ row,
                                                      const int* __restrict__ col,
                                                      const int* __restrict__ rawcnt,
                                                      unsigned int* __restrict__ tmp,
                                                      int E, int chunk) {
    __shared__ int psT[256];
    __shared__ int psC[256];
    __shared__ int biasl[256];
    __shared__ int curl[256];
    __shared__ unsigned int vall[CHUNK_CAP];
    __shared__ int destl[CHUNK_CAP];
    int blk = blockIdx.x, tid = threadIdx.x;
    int T = 0, P = 0, C = 0;
    if (tid < 256) {
        for (int b = 0; b < NB; ++b) {              // coalesced 1KB rows
            int v = rawcnt[b * 256 + tid];
            T += v;
            P += (b < blk) ? v : 0;
            C = (b == blk) ? v : C;
        }
        psT[tid] = T; psC[tid] = C;
    }
    __syncthreads();
    for (int d = 1; d < 256; d <<= 1) {             // lockstep inclusive scans
        int a = 0, c2 = 0;
        if (tid < 256 && tid >= d) { a = psT[tid - d]; c2 = psC[tid - d]; }
        __syncthreads();
        if (tid < 256 && tid >= d) { psT[tid] += a; psC[tid] += c2; }
        __syncthreads();
    }
    if (tid < 256) {
        int B = psT[tid] - T;                       // exclusive bucket base
        int loff = psC[tid] - C;                    // local exclusive offset
        biasl[tid] = B + P - loff;
        curl[tid] = loff;
    }
    __syncthreads();
    int s = blk * chunk, e = min(s + chunk, E);
    int csize = e - s;
    if (csize <= CHUNK_CAP) {
        for (int i = s + tid; i < e; i += 512) {
            int c = col[i], r = row[i];
            int k = c >> 8;
            int p = atomicAdd(&curl[k], 1);         // LDS atomic, local pos
            vall[p]  = ((unsigned)(c & 255) << 16) | (unsigned)r;
            destl[p] = biasl[k] + p;
        }
        __syncthreads();
        for (int j = tid; j < csize; j += 512)      // run-coalesced global writes
            tmp[destl[j]] = vall[j];
    } else {                                        // safety fallback
        for (int i = s + tid; i < e; i += 512) {
            int c = col[i], r = row[i];
            int k = c >> 8;
            int p = atomicAdd(&curl[k], 1);
            tmp[biasl[k] + p] = ((unsigned)(c & 255) << 16) | (unsigned)r;
        }
    }
}

// ============================================================================
// K3: per-bucket counting sort -> off/dis/eidx. Bucket bases re-derived from
// rawcnt column sums (totals array eliminated).
// ============================================================================
__global__ void __launch_bounds__(512) sort_kernel(const unsigned int* __restrict__ tmp,
                                                   const int* __restrict__ rawcnt,
                                                   int* __restrict__ off,
                                                   float* __restrict__ dis,
                                                   unsigned short* __restrict__ eidx,
                                                   int nbkt, int E, int n) {
    __shared__ int bs[256];
    __shared__ int cntT[256];
    __shared__ int cntl[256];
    __shared__ int sc[256];
    __shared__ int posr[256];
    __shared__ unsigned short el[SORT_CAP];
    int b = blockIdx.x, tid = threadIdx.x;
    int T = 0;
    if (tid < 256) {
        for (int bb = 0; bb < NB; ++bb)
            T += rawcnt[bb * 256 + tid];
        bs[tid] = T; cntT[tid] = T;
    }
    __syncthreads();
    for (int d = 1; d < 256; d <<= 1) {
        int a = 0;
        if (tid < 256 && tid >= d) a = bs[tid - d];
        __syncthreads();
        if (tid < 256 && tid >= d) bs[tid] += a;
        __syncthreads();
    }
    if (tid < 256) bs[tid] -= T;                 // exclusive bucket bases
    if (tid < 256) cntl[tid] = 0;
    __syncthreads();
    int s = bs[b];
    int cnt = cntT[b];
    int e = s + cnt;
    for (int i = s + tid; i < e; i += 512)
        atomicAdd(&cntl[tmp[i] >> 16], 1);       // LDS atomic
    __syncthreads();
    int c = 0;
    if (tid < 256) { c = cntl[tid]; sc[tid] = c; }
    __syncthreads();
    for (int d = 1; d < 256; d <<= 1) {
        int a = 0;
        if (tid < 256 && tid >= d) a = sc[tid - d];
        __syncthreads();
        if (tid < 256 && tid >= d) sc[tid] += a;
        __syncthreads();
    }
    if (tid < 256) {
        int excl = sc[tid] - c;
        int gid = (b << 8) + tid;
        if (gid < n) {
            off[gid] = s + excl;
            dis[gid] = rsqrtf((float)(c + 1));   // +1 self-loop (gcn_norm)
        }
        posr[tid] = excl;                        // relative cursor
    }
    if (b == 0 && tid == 0) off[n] = E;
    __syncthreads();
    bool staged = (cnt <= SORT_CAP);             // block-uniform
    if (staged) {
        for (int i = s + tid; i < e; i += 512) {
            unsigned int w = tmp[i];
            int p = atomicAdd(&posr[w >> 16], 1);
            el[p] = (unsigned short)(w & 0xFFFFu);   // LDS scatter
        }
        __syncthreads();
        for (int i = tid; i < cnt; i += 512)         // coalesced global write
            eidx[s + i] = el[i];
    } else {                                         // safety fallback
        for (int i = s + tid; i < e; i += 512) {
            unsigned int w = tmp[i];
            int p = atomicAdd(&posr[w >> 16], 1);
            eidx[s + p] = (unsigned short)(w & 0xFFFFu);
        }
    }
}

// ============================================================================
// Propagation hop: wave per node, 32 edges in flight.
// MODE 0 (zin = z0, unscaled): a = sum_e dis[r]*z0[r] + dis[v]*z0[v];
//                              out(half) = dis[v]^2 * a.
// MODE 1 (zin = zB, scaled):   t = zB[v] + sum_e zB[r];
//                              out(float) = dis[v]*t + bias.
// ============================================================================
#define ACC8(raw) { const __half2* h2_ = (const __half2*)&(raw);              \
    float2 f0_ = __half22float2(h2_[0]), f1_ = __half22float2(h2_[1]);        \
    float2 f2_ = __half22float2(h2_[2]), f3_ = __half22float2(h2_[3]);        \
    a0 += f0_.x; a1 += f0_.y; a2 += f1_.x; a3 += f1_.y;                       \
    a4 += f2_.x; a5 += f2_.y; a6 += f3_.x; a7 += f3_.y; }

#define FMA8(raw, dr) { const __half2* h2_ = (const __half2*)&(raw);          \
    float2 f0_ = __half22float2(h2_[0]), f1_ = __half22float2(h2_[1]);        \
    float2 f2_ = __half22float2(h2_[2]), f3_ = __half22float2(h2_[3]);        \
    a0 = fmaf(dr, f0_.x, a0); a1 = fmaf(dr, f0_.y, a1);                       \
    a2 = fmaf(dr, f1_.x, a2); a3 = fmaf(dr, f1_.y, a3);                       \
    a4 = fmaf(dr, f2_.x, a4); a5 = fmaf(dr, f2_.y, a5);                       \
    a6 = fmaf(dr, f3_.x, a6); a7 = fmaf(dr, f3_.y, a7); }

template <int MODE>
__global__ void __launch_bounds__(256) hop_kernel(const __half* __restrict__ zin,
                                                  void* __restrict__ out,
                                                  const unsigned short* __restrict__ eidx,
                                                  const int* __restrict__ off,
                                                  const float* __restrict__ dis,
                                                  const float* __restrict__ bias, int n) {
    int v = (int)((blockIdx.x * 256 + threadIdx.x) >> 6);
    if (v >= n) return;
    int lane = threadIdx.x & 63;
    int grp = lane >> 3;       // edge slot in the octet
    int sub = lane & 7;        // 16B chunk of the 128B row
    int s = off[v], e = off[v + 1];
    float dv = dis[v];         // hoisted: overlaps with gather latency
    float a0 = 0.f, a1 = 0.f, a2 = 0.f, a3 = 0.f;
    float a4 = 0.f, a5 = 0.f, a6 = 0.f, a7 = 0.f;
    if (grp == 0) {            // self-loop term
        float4 raw = ((const float4*)(zin + (size_t)v * OUT_CH))[sub];
        if (MODE == 0) { FMA8(raw, dv); } else { ACC8(raw); }
    }
    // ---- 32 edges in flight: 4 independent predicated batches ----
    int i0 = s + grp;
    int i1 = i0 + 8, i2 = i0 + 16, i3 = i0 + 24;
    bool h0 = i0 < e, h1 = i1 < e, h2 = i2 < e, h3 = i3 < e;
    int r0 = h0 ? (int)eidx[i0] : 0;
    int r1 = h1 ? (int)eidx[i1] : 0;
    int r2 = h2 ? (int)eidx[i2] : 0;
    int r3 = h3 ? (int)eidx[i3] : 0;
    float d0 = 1.f, d1 = 1.f, d2 = 1.f, d3 = 1.f;
    if (MODE == 0) {           // per-edge norm gather (8-lane broadcast, L2-hot)
        if (h0) d0 = dis[r0];
        if (h1) d1 = dis[r1];
        if (h2) d2 = dis[r2];
        if (h3) d3 = dis[r3];
    }
    float4 rA = make_float4(0.f, 0.f, 0.f, 0.f);
    float4 rB = make_float4(0.f, 0.f, 0.f, 0.f);
    float4 rC = make_float4(0.f, 0.f, 0.f, 0.f);
    float4 rD = make_float4(0.f, 0.f, 0.f, 0.f);
    if (h0) rA = ((const float4*)(zin + (size_t)r0 * OUT_CH))[sub];
    if (h1) rB = ((const float4*)(zin + (size_t)r1 * OUT_CH))[sub];
    if (h2) rC = ((const float4*)(zin + (size_t)r2 * OUT_CH))[sub];
    if (h3) rD = ((const float4*)(zin + (size_t)r3 * OUT_CH))[sub];
    if (MODE == 0) {
        FMA8(rA, d0); FMA8(rB, d1); FMA8(rC, d2); FMA8(rD, d3);
    } else {
        ACC8(rA); ACC8(rB); ACC8(rC); ACC8(rD);
    }
    if (e - s > 32) {          // rare (deg > 32): pipelined 2-batch loop
        int j0 = s + 32 + grp, j1 = j0 + 8;
        bool g0 = j0 < e, g1 = j1 < e;
        int q0 = g0 ? (int)eidx[j0] : 0;
        int q1 = g1 ? (int)eidx[j1] : 0;
        while (g0) {           // g1 implies g0
            int k0 = j0 + 16, k1 = j1 + 16;
            bool f0 = k0 < e, f1 = k1 < e;
            int p0 = f0 ? (int)eidx[k0] : 0;   // prefetch next descriptors
            int p1 = f1 ? (int)eidx[k1] : 0;
            float dq0 = 1.f, dq1 = 1.f;
            if (MODE == 0) {
                if (g0) dq0 = dis[q0];
                if (g1) dq1 = dis[q1];
            }
            float4 xA = make_float4(0.f, 0.f, 0.f, 0.f);
            float4 xB = make_float4(0.f, 0.f, 0.f, 0.f);
            if (g0) xA = ((const float4*)(zin + (size_t)q0 * OUT_CH))[sub];
            if (g1) xB = ((const float4*)(zin + (size_t)q1 * OUT_CH))[sub];
            if (MODE == 0) { FMA8(xA, dq0); FMA8(xB, dq1); }
            else           { ACC8(xA); ACC8(xB); }
            j0 = k0; j1 = k1; q0 = p0; q1 = p1; g0 = f0; g1 = f1;
        }
    }
    // reduce the 8 edge slots (lanes differing in bits 3..5)
#pragma unroll
    for (int m = 8; m <= 32; m <<= 1) {
        a0 += __shfl_xor(a0, m, 64); a1 += __shfl_xor(a1, m, 64);
        a2 += __shfl_xor(a2, m, 64); a3 += __shfl_xor(a3, m, 64);
        a4 += __shfl_xor(a4, m, 64); a5 += __shfl_xor(a5, m, 64);
        a6 += __shfl_xor(a6, m, 64); a7 += __shfl_xor(a7, m, 64);
    }
    if (grp == 0) {
        if (MODE == 0) {
            float sc = dv * dv;
            union { __half2 h[4]; float4 f; } u;
            u.h[0] = __floats2half2_rn(sc * a0, sc * a1);
            u.h[1] = __floats2half2_rn(sc * a2, sc * a3);
            u.h[2] = __floats2half2_rn(sc * a4, sc * a5);
            u.h[3] = __floats2half2_rn(sc * a6, sc * a7);
            ((float4*)((__half*)out + (size_t)v * OUT_CH))[sub] = u.f;
        } else {
            const float4* bp = (const float4*)(bias + sub * 8);
            float4 b0 = bp[0], b1 = bp[1];
            float* op = (float*)out + (size_t)v * OUT_CH + sub * 8;
            *(float4*)op = make_float4(fmaf(dv, a0, b0.x), fmaf(dv, a1, b0.y),
                                       fmaf(dv, a2, b0.z), fmaf(dv, a3, b0.w));
            *(float4*)(op + 4) = make_float4(fmaf(dv, a4, b1.x), fmaf(dv, a5, b1.y),
                                             fmaf(dv, a6, b1.z), fmaf(dv, a7, b1.w));
        }
    }
}

extern "C" void kernel_launch(void* const* d_in, const int* in_sizes, int n_in,
                              void* d_out, int out_size, void* d_ws, size_t ws_size,
                              hipStream_t stream) {
    const float* x = (const float*)d_in[0];
    const int* ei = (const int*)d_in[1];
    const float* W = (const float*)d_in[2];
    const float* b = (const float*)d_in[3];
    int n = in_sizes[0] / IN_CH;   // 50000
    int E = in_sizes[1] / 2;       // 800000
    const int* row = ei;           // edge_index[0] = source
    const int* col = ei + E;       // edge_index[1] = target

    char* ws = (char*)d_ws;
    size_t o = 0;
    auto alloc = [&](size_t bytes) -> void* {
        void* p = ws + o;
        o += (bytes + 255) & ~(size_t)255;
        return p;
    };
    int nbkt = (n + 255) >> 8;      // 196
    int chunk = (E + NB - 1) / NB;  // 3125
    int GB = (n + 63) / 64;         // 782 gemm blocks

    int*            rawcnt = (int*)alloc((size_t)NB * 256 * 4);
    unsigned int*   tmp    = (unsigned int*)alloc((size_t)E * 4);
    int*            off    = (int*)alloc((size_t)(n + 1) * 4);
    float*          dis    = (float*)alloc((size_t)n * 4);
    unsigned short* eidx   = (unsigned short*)alloc((size_t)E * 2);
    __half*         zA     = (__half*)alloc((size_t)n * OUT_CH * 2);
    __half*         zB     = (__half*)alloc((size_t)n * OUT_CH * 2);

    fat1_kernel<<<GB + NB, 256, 0, stream>>>(x, W, zA, col, rawcnt, n, E, chunk, GB);
    scatter_kernel<<<NB, 512, 0, stream>>>(row, col, rawcnt, tmp, E, chunk);
    sort_kernel<<<nbkt, 512, 0, stream>>>(tmp, rawcnt, off, dis, eidx, nbkt, E, n);
    int hopBlocks = (n + 3) / 4;   // wave per node
    hop_kernel<0><<<hopBlocks, 256, 0, stream>>>(zA, zB, eidx, off, dis, nullptr, n);
    hop_kernel<1><<<hopBlocks, 256, 0, stream>>>(zB, d_out, eidx, off, dis, b, n);
}